// Round 4
// baseline (808.661 us; speedup 1.0000x reference)
//
#include <hip/hip_runtime.h>

#define NBLK_BIN 512   // bin-pass blocks (2 per CU)
#define NBKT 196       // ceil(100000/512) dst-buckets
#define BWIN 512       // nodes per bucket
#define CAP 64         // global pairs slots (int2) per (block,bucket); mean 31.9
#define SCAP 36        // LDS staging slots per bucket (remainder<=7 + <=29 new)
#define OVF_CAP 65536  // overflow list capacity (statistically unused)
#define ITER_EDGES 1024

// ---------------- CSR build: bin pass ----------------
// Appends go to LDS staging; only FULL 64B lines are flushed to the block's
// private global cell (int4 stores) -> HBM write ~= payload. Overflow (rare,
// deterministic-safe) goes to a global list.
__global__ __launch_bounds__(256) void bin_kernel(const int* __restrict__ src,
                                                  const int* __restrict__ dst,
                                                  int2* __restrict__ pairs,
                                                  int* __restrict__ blkcnt,
                                                  int2* __restrict__ ovf,
                                                  int* __restrict__ ovf_cnt, int e) {
    __shared__ __align__(16) int2 stage[NBKT][SCAP];   // 56.4 KB
    __shared__ int lcnt[NBKT];
    __shared__ int gcur[NBKT];
    int blk = blockIdx.x, tid = threadIdx.x;
    for (int t = tid; t < NBKT; t += 256) { lcnt[t] = 0; gcur[t] = 0; }
    __syncthreads();
    int chunk = (e + NBLK_BIN - 1) / NBLK_BIN;
    int base = blk * chunk;
    int end = min(e, base + chunk);
    for (int ib = base; ib < end; ib += ITER_EDGES) {
        int iend = min(end, ib + ITER_EDGES);
        // phase A: append to LDS staging
        for (int i = ib + tid; i < iend; i += 256) {
            int s = src[i], d = dst[i];
            int b = d >> 9;
            int pos = atomicAdd(&lcnt[b], 1);
            if (pos < SCAP) stage[b][pos] = make_int2(s, d);
            else { int p = atomicAdd(ovf_cnt, 1); if (p < OVF_CAP) ovf[p] = make_int2(s, d); }
        }
        __syncthreads();
        // phase B: flush full 64B lines, thread-per-bucket
        if (tid < NBKT) {
            int b = tid;
            int c = min(lcnt[b], SCAP);
            int nl = c >> 3;
            int g = gcur[b];
            int4* cell = (int4*)(pairs + ((size_t)blk * NBKT + b) * CAP);
            const int4* st = (const int4*)&stage[b][0];
            for (int l = 0; l < nl; ++l) {
                if (g + 8 <= CAP) {
                    int o = g >> 1;
                    cell[o]     = st[l * 4];
                    cell[o + 1] = st[l * 4 + 1];
                    cell[o + 2] = st[l * 4 + 2];
                    cell[o + 3] = st[l * 4 + 3];
                    g += 8;
                } else {
                    int p = atomicAdd(ovf_cnt, 8);
                    for (int k = 0; k < 8; ++k)
                        if (p + k < OVF_CAP) ovf[p + k] = stage[b][l * 8 + k];
                }
            }
            gcur[b] = g;
            int rem = c & 7;
            for (int k = 0; k < rem; ++k) stage[b][k] = stage[b][nl * 8 + k];
            lcnt[b] = rem;
        }
        __syncthreads();
    }
    // final flush of remainders (pad to full line when room; garbage beyond
    // count is never read since blkcnt bounds it)
    if (tid < NBKT) {
        int b = tid;
        int rem = min(lcnt[b], SCAP);
        int g = gcur[b];
        if (g + 8 <= CAP) {
            int4* cell = (int4*)(pairs + ((size_t)blk * NBKT + b) * CAP);
            const int4* st = (const int4*)&stage[b][0];
            int o = g >> 1;
            cell[o] = st[0]; cell[o + 1] = st[1]; cell[o + 2] = st[2]; cell[o + 3] = st[3];
            g += rem;
        } else if (g + rem <= CAP) {
            for (int k = 0; k < rem; ++k)
                pairs[((size_t)blk * NBKT + b) * CAP + g + k] = stage[b][k];
            g += rem;
        } else {
            int p = atomicAdd(ovf_cnt, rem);
            for (int k = 0; k < rem; ++k)
                if (p + k < OVF_CAP) ovf[p + k] = stage[b][k];
        }
        blkcnt[(size_t)b * NBLK_BIN + blk] = g;   // b-major for coalesced reads later
    }
}

// ---------------- bucket totals -> exclusive bases (1 block) ----------------
__global__ __launch_bounds__(256) void bucket_scan_kernel(const int* __restrict__ blkcnt,
                                                          const int2* __restrict__ ovf,
                                                          const int* __restrict__ ovf_cnt,
                                                          int* __restrict__ bucket_base) {
    __shared__ int bt[256];
    int tid = threadIdx.x;
    int sum = 0;
    if (tid < NBKT) {
        const int4* row = (const int4*)(blkcnt + (size_t)tid * NBLK_BIN);
        for (int i = 0; i < NBLK_BIN / 4; ++i) {
            int4 v4 = row[i];
            sum += v4.x + v4.y + v4.z + v4.w;
        }
    }
    bt[tid] = sum;
    __syncthreads();
    int novf = min(*ovf_cnt, OVF_CAP);
    for (int i = tid; i < novf; i += 256) atomicAdd(&bt[ovf[i].y >> 9], 1);
    __syncthreads();
    int v = bt[tid];
    for (int off = 1; off < 256; off <<= 1) {
        int t = (tid >= off) ? bt[tid - off] : 0;
        __syncthreads();
        bt[tid] += t;
        __syncthreads();
    }
    if (tid < NBKT) bucket_base[tid] = bt[tid] - v;
}

// ---------------- CSR build: fill pass (+ cnt/rowptr/dinv) ----------------
__global__ __launch_bounds__(256) void fill_kernel(const int2* __restrict__ pairs,
                                                   const int* __restrict__ blkcnt,
                                                   const int* __restrict__ bucket_base,
                                                   const int2* __restrict__ ovf,
                                                   const int* __restrict__ ovf_cnt,
                                                   int* __restrict__ srcs,
                                                   int* __restrict__ cnt,
                                                   int* __restrict__ rowptr,
                                                   float* __restrict__ dinv, int n) {
    __shared__ int lc[BWIN];
    __shared__ int lofs[BWIN];
    __shared__ int psum[256];
    __shared__ int sm[NBLK_BIN];
    int b = blockIdx.x, tid = threadIdx.x;
    int nbase = b << 9;
    for (int t = tid; t < BWIN; t += 256) lc[t] = 0;
    for (int t = tid; t < NBLK_BIN; t += 256) sm[t] = blkcnt[(size_t)b * NBLK_BIN + t];
    __syncthreads();
    int wave = tid >> 6, lane = tid & 63;
    // pass 1: per-node counts
    for (int blk = wave; blk < NBLK_BIN; blk += 4) {
        int m = sm[blk];
        const int2* p = pairs + ((size_t)blk * NBKT + b) * CAP;
        for (int i = lane; i < m; i += 64) atomicAdd(&lc[p[i].y - nbase], 1);
    }
    int novf = min(*ovf_cnt, OVF_CAP);
    for (int i = tid; i < novf; i += 256) {
        int d = ovf[i].y;
        if ((d >> 9) == b) atomicAdd(&lc[d - nbase], 1);
    }
    __syncthreads();
    // exclusive scan of 512 counts with 256 threads
    int a0 = lc[2 * tid], a1 = lc[2 * tid + 1];
    psum[tid] = a0 + a1;
    __syncthreads();
    int v = psum[tid];
    for (int off = 1; off < 256; off <<= 1) {
        int t = (tid >= off) ? psum[tid - off] : 0;
        __syncthreads();
        psum[tid] += t;
        __syncthreads();
    }
    int ex = psum[tid] - v;
    lofs[2 * tid] = ex;
    lofs[2 * tid + 1] = ex + a0;
    __syncthreads();
    int gbase = bucket_base[b];
    for (int t = tid; t < BWIN; t += 256) {
        int vtx = nbase + t;
        if (vtx < n) {
            int c = lc[t];
            cnt[vtx] = c;
            rowptr[vtx] = gbase + lofs[t];
            dinv[vtx] = rsqrtf(1.0f + (float)c);   // +1: self-loop
        }
    }
    __syncthreads();
    for (int t = tid; t < BWIN; t += 256) lc[t] = lofs[t];   // reuse as cursor
    __syncthreads();
    // pass 2: place
    for (int blk = wave; blk < NBLK_BIN; blk += 4) {
        int m = sm[blk];
        const int2* p = pairs + ((size_t)blk * NBKT + b) * CAP;
        for (int i = lane; i < m; i += 64) {
            int2 e2 = p[i];
            int o = atomicAdd(&lc[e2.y - nbase], 1);
            srcs[gbase + o] = e2.x;
        }
    }
    for (int i = tid; i < novf; i += 256) {
        int2 e2 = ovf[i];
        if ((e2.y >> 9) == b) {
            int o = atomicAdd(&lc[e2.y - nbase], 1);
            srcs[gbase + o] = e2.x;
        }
    }
}

// ---------------- input feature build (stride 8) ----------------

__global__ __launch_bounds__(256) void build_x0_kernel(const float* __restrict__ coords,
                                                       const int* __restrict__ at,
                                                       const float* __restrict__ emb,
                                                       float* __restrict__ x, int n) {
    int v = blockIdx.x * 256 + threadIdx.x;
    if (v >= n) return;
    float* row = x + (size_t)v * 8;
    row[0] = coords[3 * v + 0];
    row[1] = coords[3 * v + 1];
    row[2] = coords[3 * v + 2];
    int t = at[v];
    row[3] = emb[3 * t + 0];
    row[4] = emb[3 * t + 1];
    row[5] = emb[3 * t + 2];
}

// ---------------- layer building blocks ----------------

template <int F, int FP>
__global__ __launch_bounds__(256) void scale_inplace_kernel(float* __restrict__ x,
                                                            const float* __restrict__ dinv,
                                                            int istride, int n) {
    int gid = blockIdx.x * 256 + threadIdx.x;
    int v = gid / FP, j = gid % FP;
    if (v >= n || j >= F) return;
    x[(size_t)v * istride + j] *= dinv[v];
}

// out[v][j] = op( dinv[v] * (in[v][j] + sum_{s in row(v)} in[s][j]) [+ b[j]] )
template <int F, int FP, bool HAS_BIAS, bool RELU>
__global__ __launch_bounds__(256) void agg_kernel(const float* __restrict__ in,
                                                  const float* __restrict__ dinv,
                                                  const int* __restrict__ rowptr,
                                                  const int* __restrict__ cnt,
                                                  const int* __restrict__ srcs,
                                                  const float* __restrict__ b,
                                                  float* __restrict__ out,
                                                  int istride, int ostride, int n) {
    int gid = blockIdx.x * 256 + threadIdx.x;
    int v = gid / FP, j = gid % FP;
    if (v >= n || j >= F) return;
    float dv = dinv[v];
    int start = rowptr[v];
    int len = cnt[v];
    float acc = in[(size_t)v * istride + j];   // self-loop (pre-scaled by dinv[v])
    int k = 0;
    for (; k + 4 <= len; k += 4) {
        int s0 = srcs[start + k];
        int s1 = srcs[start + k + 1];
        int s2 = srcs[start + k + 2];
        int s3 = srcs[start + k + 3];
        float a0 = in[(size_t)s0 * istride + j];
        float a1 = in[(size_t)s1 * istride + j];
        float a2 = in[(size_t)s2 * istride + j];
        float a3 = in[(size_t)s3 * istride + j];
        acc += (a0 + a1) + (a2 + a3);
    }
    for (; k < len; ++k) {
        int s = srcs[start + k];
        acc += in[(size_t)s * istride + j];
    }
    float val = acc * dv;
    if (HAS_BIAS) val += b[j];
    if (RELU) val = fmaxf(val, 0.0f);
    out[(size_t)v * ostride + j] = val;
}

template <int DIN, int DOUT, int DOUTP, bool RELU>
__global__ __launch_bounds__(256) void gemm_bias_kernel(const float* __restrict__ xin,
                                                        const float* __restrict__ W,
                                                        const float* __restrict__ b,
                                                        float* __restrict__ xout,
                                                        int istride, int ostride, int n) {
    __shared__ float wlds[DIN * DOUT];
    for (int i = threadIdx.x; i < DIN * DOUT; i += 256) wlds[i] = W[i];
    __syncthreads();
    int gid = blockIdx.x * 256 + threadIdx.x;
    int v = gid / DOUTP, j = gid % DOUTP;
    if (v >= n || j >= DOUT) return;
    const float* xr = xin + (size_t)v * istride;
    float acc = 0.0f;
#pragma unroll
    for (int k = 0; k < DIN; ++k) acc = fmaf(xr[k], wlds[k * DOUT + j], acc);
    float val = acc + b[j];
    if (RELU) val = fmaxf(val, 0.0f);
    xout[(size_t)v * ostride + j] = val;
}

template <int DIN, int DOUT, int DOUTP>
__global__ __launch_bounds__(256) void gemm_scale_kernel(const float* __restrict__ xin,
                                                         const float* __restrict__ W,
                                                         const float* __restrict__ dinv,
                                                         float* __restrict__ h,
                                                         int istride, int ostride, int n) {
    __shared__ float wlds[DIN * DOUT];
    for (int i = threadIdx.x; i < DIN * DOUT; i += 256) wlds[i] = W[i];
    __syncthreads();
    int gid = blockIdx.x * 256 + threadIdx.x;
    int v = gid / DOUTP, j = gid % DOUTP;
    if (v >= n || j >= DOUT) return;
    const float* xr = xin + (size_t)v * istride;
    float acc = 0.0f;
#pragma unroll
    for (int k = 0; k < DIN; ++k) acc = fmaf(xr[k], wlds[k * DOUT + j], acc);
    h[(size_t)v * ostride + j] = acc * dinv[v];
}

// ---------------- driver ----------------

extern "C" void kernel_launch(void* const* d_in, const int* in_sizes, int n_in,
                              void* d_out, int out_size, void* d_ws, size_t ws_size,
                              hipStream_t stream) {
    const float* coords = (const float*)d_in[0];
    const int* at       = (const int*)d_in[1];
    const int* ei       = (const int*)d_in[2];
    const float* emb    = (const float*)d_in[3];
    const float* W1 = (const float*)d_in[4];  const float* b1 = (const float*)d_in[5];
    const float* W2 = (const float*)d_in[6];  const float* b2 = (const float*)d_in[7];
    const float* W3 = (const float*)d_in[8];  const float* b3 = (const float*)d_in[9];
    const float* W4 = (const float*)d_in[10]; const float* b4 = (const float*)d_in[11];
    const float* W5 = (const float*)d_in[12]; const float* b5 = (const float*)d_in[13];
    float* out = (float*)d_out;

    const int n = in_sizes[0] / 3;   // 100000
    const int e = in_sizes[2] / 2;   // 3200000
    const int* src = ei;
    const int* dst = ei + e;

    // workspace layout (pairs dies before A/B are born -> alias). ~66 MB total.
    char* ws = (char*)d_ws;
    size_t off = 0;
    float* dinv   = (float*)(ws + off); off += (size_t)n * 4;          // 400000
    int*   cnt    = (int*)(ws + off);   off += (size_t)n * 4;
    int*   rowptr = (int*)(ws + off);   off += (size_t)n * 4;
    int*   bbase  = (int*)(ws + off);   off += 1024;                   // bucket_base
    int*   ovfcnt = (int*)(ws + off);   off += 16;
    int*   blkcnt = (int*)(ws + off);   off += (size_t)NBKT * NBLK_BIN * 4;
    int2*  ovf    = (int2*)(ws + off);  off += (size_t)OVF_CAP * 8;
    int*   srcs   = (int*)(ws + off);   off += (size_t)e * 4;
    char*  alias  = ws + off;           // max(pairs 51.38MB, A+B 51.2MB)
    int2*  pairs  = (int2*)alias;
    float* A      = (float*)alias;
    float* B      = A + (size_t)n * 64;

    int nb = (n + 255) / 256;   // 391

    // ---- CSR build ----
    hipMemsetAsync(ovfcnt, 0, 4, stream);
    bin_kernel<<<NBLK_BIN, 256, 0, stream>>>(src, dst, pairs, blkcnt, ovf, ovfcnt, e);
    bucket_scan_kernel<<<1, 256, 0, stream>>>(blkcnt, ovf, ovfcnt, bbase);
    fill_kernel<<<NBKT, 256, 0, stream>>>(pairs, blkcnt, bbase, ovf, ovfcnt,
                                          srcs, cnt, rowptr, dinv, n);

    // ---- x0 = [coords, emb[atom_types]], stride 8, in A (overwrites pairs) ----
    build_x0_kernel<<<nb, 256, 0, stream>>>(coords, at, emb, A, n);

    auto blocks = [](long long threads) { return (int)((threads + 255) / 256); };

    // L1: 6->32, pre-agg width 6 (stride 8)
    scale_inplace_kernel<6, 8><<<blocks((long long)n * 8), 256, 0, stream>>>(A, dinv, 8, n);
    agg_kernel<6, 8, false, false><<<blocks((long long)n * 8), 256, 0, stream>>>(
        A, dinv, rowptr, cnt, srcs, nullptr, B, 8, 8, n);
    gemm_bias_kernel<6, 32, 32, true><<<blocks((long long)n * 32), 256, 0, stream>>>(
        B, W1, b1, A, 8, 32, n);

    // L2: 32->64, pre-agg width 32
    scale_inplace_kernel<32, 32><<<blocks((long long)n * 32), 256, 0, stream>>>(A, dinv, 32, n);
    agg_kernel<32, 32, false, false><<<blocks((long long)n * 32), 256, 0, stream>>>(
        A, dinv, rowptr, cnt, srcs, nullptr, B, 32, 32, n);
    gemm_bias_kernel<32, 64, 64, true><<<blocks((long long)n * 64), 256, 0, stream>>>(
        B, W2, b2, A, 32, 64, n);

    // L3: 64->64, pre-agg width 64
    scale_inplace_kernel<64, 64><<<blocks((long long)n * 64), 256, 0, stream>>>(A, dinv, 64, n);
    agg_kernel<64, 64, false, false><<<blocks((long long)n * 64), 256, 0, stream>>>(
        A, dinv, rowptr, cnt, srcs, nullptr, B, 64, 64, n);
    gemm_bias_kernel<64, 64, 64, true><<<blocks((long long)n * 64), 256, 0, stream>>>(
        B, W3, b3, A, 64, 64, n);

    // L4: 64->32, post-agg width 32 (agg does bias+relu)
    gemm_scale_kernel<64, 32, 32><<<blocks((long long)n * 32), 256, 0, stream>>>(
        A, W4, dinv, B, 64, 32, n);
    agg_kernel<32, 32, true, true><<<blocks((long long)n * 32), 256, 0, stream>>>(
        B, dinv, rowptr, cnt, srcs, b4, A, 32, 32, n);

    // L5: 32->3, post-agg width 3 (agg does bias, no relu) -> d_out stride 3
    gemm_scale_kernel<32, 3, 4><<<blocks((long long)n * 4), 256, 0, stream>>>(
        A, W5, dinv, B, 32, 4, n);
    agg_kernel<3, 4, true, false><<<blocks((long long)n * 4), 256, 0, stream>>>(
        B, dinv, rowptr, cnt, srcs, b5, out, 4, 3, n);
}

// Round 5
// 572.962 us; speedup vs baseline: 1.4114x; 1.4114x over previous
//
#include <hip/hip_runtime.h>
#include <hip/hip_fp16.h>

#define NBLK_BIN 256   // persistent blocks in bin pass
#define NBKT 196       // ceil(100000/512) dst-buckets
#define BWIN 512       // nodes per bucket
#define CAP 128        // slots per (block,bucket); mean 64, sigma 8 -> 8-sigma slack

typedef unsigned int uint;

union U32H2 { uint u; __half2 h; };

__device__ inline float2 h2_to_f2(uint u) {
    U32H2 c; c.u = u;
    return __half22float2(c.h);
}
__device__ inline uint f2_to_h2(float a, float b) {
    U32H2 c; c.h = __floats2half2_rn(a, b);
    return c.u;
}

// ---------------- CSR build (round-3 structure) ----------------

__global__ __launch_bounds__(256) void zero_cnt_kernel(int* cnt, int n) {
    int i = blockIdx.x * 256 + threadIdx.x;
    if (i < n) cnt[i] = 0;
}

// Each block owns pairs[blk][bucket][0..CAP) privately; degree count fused in.
__global__ __launch_bounds__(256) void bin_kernel(const int* __restrict__ src,
                                                  const int* __restrict__ dst,
                                                  int* __restrict__ cnt,
                                                  int2* __restrict__ pairs,
                                                  int* __restrict__ blkcnt, int e) {
    __shared__ int lcnt[NBKT];
    int blk = blockIdx.x;
    for (int t = threadIdx.x; t < NBKT; t += 256) lcnt[t] = 0;
    __syncthreads();
    int chunk = (e + NBLK_BIN - 1) / NBLK_BIN;
    int base = blk * chunk;
    int end = min(e, base + chunk);
    for (int i = base + threadIdx.x; i < end; i += 256) {
        int s = src[i], d = dst[i];
        atomicAdd(&cnt[d], 1);
        int b = d >> 9;
        int pos = atomicAdd(&lcnt[b], 1);
        if (pos < CAP) pairs[((size_t)blk * NBKT + b) * CAP + pos] = make_int2(s, d);
    }
    __syncthreads();
    for (int t = threadIdx.x; t < NBKT; t += 256) blkcnt[blk * NBKT + t] = min(lcnt[t], CAP);
}

__global__ __launch_bounds__(256) void fill_csr_kernel2(const int2* __restrict__ pairs,
                                                        const int* __restrict__ blkcnt,
                                                        const int* __restrict__ rowptr,
                                                        int* __restrict__ srcs, int n) {
    __shared__ int lcur[BWIN];
    __shared__ int sm[NBLK_BIN];
    int b = blockIdx.x;
    int nbase = b * BWIN;
    for (int t = threadIdx.x; t < BWIN; t += 256) lcur[t] = 0;
    for (int t = threadIdx.x; t < NBLK_BIN; t += 256) sm[t] = blkcnt[t * NBKT + b];
    __syncthreads();
    int wave = threadIdx.x >> 6, lane = threadIdx.x & 63;
    for (int blk = wave; blk < NBLK_BIN; blk += 4) {
        int m = sm[blk];
        const int2* p = pairs + ((size_t)blk * NBKT + b) * CAP;
        for (int i = lane; i < m; i += 64) {
            int2 e2 = p[i];
            int off = atomicAdd(&lcur[e2.y - nbase], 1);
            srcs[rowptr[e2.y] + off] = e2.x;
        }
    }
}

__global__ __launch_bounds__(256) void dinv_kernel(const int* __restrict__ cnt, float* __restrict__ dinv, int n) {
    int i = blockIdx.x * 256 + threadIdx.x;
    if (i < n) dinv[i] = rsqrtf(1.0f + (float)cnt[i]);   // +1: self-loop, deg >= 1 always
}

__global__ __launch_bounds__(256) void scan_partial_kernel(const int* __restrict__ cnt,
                                                           int* __restrict__ rowptr,
                                                           int* __restrict__ bsum, int n) {
    __shared__ int lds[256];
    int i = blockIdx.x * 256 + threadIdx.x;
    int v = (i < n) ? cnt[i] : 0;
    lds[threadIdx.x] = v;
    __syncthreads();
    for (int off = 1; off < 256; off <<= 1) {
        int t = (threadIdx.x >= off) ? lds[threadIdx.x - off] : 0;
        __syncthreads();
        lds[threadIdx.x] += t;
        __syncthreads();
    }
    if (i < n) rowptr[i] = lds[threadIdx.x] - v;           // exclusive
    if (threadIdx.x == 255) bsum[blockIdx.x] = lds[255];   // block total
}

__global__ __launch_bounds__(512) void scan_sums_kernel(int* __restrict__ bsum, int nb) {
    __shared__ int lds[512];
    int tid = threadIdx.x;
    int v = (tid < nb) ? bsum[tid] : 0;
    lds[tid] = v;
    __syncthreads();
    for (int off = 1; off < 512; off <<= 1) {
        int t = (tid >= off) ? lds[tid - off] : 0;
        __syncthreads();
        lds[tid] += t;
        __syncthreads();
    }
    if (tid < nb) bsum[tid] = lds[tid] - v;                // exclusive
}

__global__ __launch_bounds__(256) void add_offsets_kernel(int* __restrict__ rowptr,
                                                          const int* __restrict__ bsum, int n) {
    int i = blockIdx.x * 256 + threadIdx.x;
    if (i < n) rowptr[i] += bsum[blockIdx.x];
}

// ---------------- input feature build: half, stride 8, pre-scaled by dinv ----------------

__global__ __launch_bounds__(256) void build_x0_h_kernel(const float* __restrict__ coords,
                                                         const int* __restrict__ at,
                                                         const float* __restrict__ emb,
                                                         const float* __restrict__ dinv,
                                                         uint* __restrict__ x, int n) {
    int v = blockIdx.x * 256 + threadIdx.x;
    if (v >= n) return;
    float dv = dinv[v];
    float c0 = coords[3 * v + 0] * dv;
    float c1 = coords[3 * v + 1] * dv;
    float c2 = coords[3 * v + 2] * dv;
    int t = at[v];
    float e0 = emb[3 * t + 0] * dv;
    float e1 = emb[3 * t + 1] * dv;
    float e2 = emb[3 * t + 2] * dv;
    uint* row = x + (size_t)v * 4;   // 8 halfs = 4 uints
    row[0] = f2_to_h2(c0, c1);
    row[1] = f2_to_h2(c2, e0);
    row[2] = f2_to_h2(e1, e2);
    row[3] = 0;                       // zero pad (features 6,7)
}

// ---------------- packed-half aggregation ----------------
// out[v] = op( dinv[v] * (in[v] + sum_{s in row(v)} in[s]) [+ b] ), all rows
// pre-scaled by dinv[src]. Each lane owns 2 features (one uint). stride = FPH2 uints.
template <int FPH2, bool HAS_BIAS, bool RELU>
__global__ __launch_bounds__(256) void agg_h_kernel(const uint* __restrict__ in,
                                                    const float* __restrict__ dinv,
                                                    const int* __restrict__ rowptr,
                                                    const int* __restrict__ cnt,
                                                    const int* __restrict__ srcs,
                                                    const float* __restrict__ bias,
                                                    uint* __restrict__ out, int n) {
    int gid = blockIdx.x * 256 + threadIdx.x;
    int v = gid / FPH2, j2 = gid % FPH2;
    if (v >= n) return;
    float2 s0 = h2_to_f2(in[(size_t)v * FPH2 + j2]);   // self term
    float accx = s0.x, accy = s0.y;
    int start = rowptr[v];
    int len = cnt[v];
    int k = 0;
    for (; k + 4 <= len; k += 4) {
        int sA = srcs[start + k];
        int sB = srcs[start + k + 1];
        int sC = srcs[start + k + 2];
        int sD = srcs[start + k + 3];
        float2 fA = h2_to_f2(in[(size_t)sA * FPH2 + j2]);
        float2 fB = h2_to_f2(in[(size_t)sB * FPH2 + j2]);
        float2 fC = h2_to_f2(in[(size_t)sC * FPH2 + j2]);
        float2 fD = h2_to_f2(in[(size_t)sD * FPH2 + j2]);
        accx += (fA.x + fB.x) + (fC.x + fD.x);
        accy += (fA.y + fB.y) + (fC.y + fD.y);
    }
    for (; k < len; ++k) {
        int s = srcs[start + k];
        float2 f = h2_to_f2(in[(size_t)s * FPH2 + j2]);
        accx += f.x; accy += f.y;
    }
    float dv = dinv[v];
    accx *= dv; accy *= dv;
    if (HAS_BIAS) { accx += bias[2 * j2]; accy += bias[2 * j2 + 1]; }
    if (RELU) { accx = fmaxf(accx, 0.0f); accy = fmaxf(accy, 0.0f); }
    out[(size_t)v * FPH2 + j2] = f2_to_h2(accx, accy);
}

// ---------------- half GEMM: fp32 accumulate, packed-half (or fp32) out ----------------
// val = acc; if HAS_BIAS val+=b; if RELU relu; if SCALE val*=dinv[v].
template <int DIN, int DOUT, int DOUTH2, bool HAS_BIAS, bool RELU, bool SCALE, bool OUTF>
__global__ __launch_bounds__(256) void gemm_h_kernel(const uint* __restrict__ xin,
                                                     const float* __restrict__ W,
                                                     const float* __restrict__ bias,
                                                     const float* __restrict__ dinv,
                                                     void* __restrict__ xout,
                                                     int istride_u, int ostride, int n) {
    __shared__ float wlds[DIN * DOUT];
    for (int i = threadIdx.x; i < DIN * DOUT; i += 256) wlds[i] = W[i];
    __syncthreads();
    int gid = blockIdx.x * 256 + threadIdx.x;
    int v = gid / DOUTH2, j2 = gid % DOUTH2;
    if (v >= n) return;
    int j1 = 2 * j2;
    const uint* xr = xin + (size_t)v * istride_u;
    float acc0 = 0.0f, acc1 = 0.0f;
#pragma unroll
    for (int ku = 0; ku < DIN / 2; ++ku) {
        float2 xf = h2_to_f2(xr[ku]);
        int k = 2 * ku;
        acc0 = fmaf(xf.x, wlds[k * DOUT + j1], acc0);
        acc0 = fmaf(xf.y, wlds[(k + 1) * DOUT + j1], acc0);
        if (j1 + 1 < DOUT) {
            acc1 = fmaf(xf.x, wlds[k * DOUT + j1 + 1], acc1);
            acc1 = fmaf(xf.y, wlds[(k + 1) * DOUT + j1 + 1], acc1);
        }
    }
    if (HAS_BIAS) {
        acc0 += bias[j1];
        if (j1 + 1 < DOUT) acc1 += bias[j1 + 1];
    }
    if (RELU) { acc0 = fmaxf(acc0, 0.0f); acc1 = fmaxf(acc1, 0.0f); }
    if (SCALE) { float dv = dinv[v]; acc0 *= dv; acc1 *= dv; }
    if (OUTF) {
        float* o = (float*)xout + (size_t)v * ostride;
        o[j1] = acc0;
        if (j1 + 1 < DOUT) o[j1 + 1] = acc1;
    } else {
        ((uint*)xout)[(size_t)v * ostride + j2] = f2_to_h2(acc0, acc1);
    }
}

// ---------------- fp32 final aggregation (L5) ----------------
template <int F, int FP, bool HAS_BIAS, bool RELU>
__global__ __launch_bounds__(256) void agg_f_kernel(const float* __restrict__ in,
                                                    const float* __restrict__ dinv,
                                                    const int* __restrict__ rowptr,
                                                    const int* __restrict__ cnt,
                                                    const int* __restrict__ srcs,
                                                    const float* __restrict__ b,
                                                    float* __restrict__ out,
                                                    int istride, int ostride, int n) {
    int gid = blockIdx.x * 256 + threadIdx.x;
    int v = gid / FP, j = gid % FP;
    if (v >= n || j >= F) return;
    float dv = dinv[v];
    int start = rowptr[v];
    int len = cnt[v];
    float acc = in[(size_t)v * istride + j];
    int k = 0;
    for (; k + 4 <= len; k += 4) {
        int s0 = srcs[start + k];
        int s1 = srcs[start + k + 1];
        int s2 = srcs[start + k + 2];
        int s3 = srcs[start + k + 3];
        float a0 = in[(size_t)s0 * istride + j];
        float a1 = in[(size_t)s1 * istride + j];
        float a2 = in[(size_t)s2 * istride + j];
        float a3 = in[(size_t)s3 * istride + j];
        acc += (a0 + a1) + (a2 + a3);
    }
    for (; k < len; ++k) acc += in[(size_t)srcs[start + k] * istride + j];
    float val = acc * dv;
    if (HAS_BIAS) val += b[j];
    if (RELU) val = fmaxf(val, 0.0f);
    out[(size_t)v * ostride + j] = val;
}

// ---------------- driver ----------------

extern "C" void kernel_launch(void* const* d_in, const int* in_sizes, int n_in,
                              void* d_out, int out_size, void* d_ws, size_t ws_size,
                              hipStream_t stream) {
    const float* coords = (const float*)d_in[0];
    const int* at       = (const int*)d_in[1];
    const int* ei       = (const int*)d_in[2];
    const float* emb    = (const float*)d_in[3];
    const float* W1 = (const float*)d_in[4];  const float* b1 = (const float*)d_in[5];
    const float* W2 = (const float*)d_in[6];  const float* b2 = (const float*)d_in[7];
    const float* W3 = (const float*)d_in[8];  const float* b3 = (const float*)d_in[9];
    const float* W4 = (const float*)d_in[10]; const float* b4 = (const float*)d_in[11];
    const float* W5 = (const float*)d_in[12]; const float* b5 = (const float*)d_in[13];
    float* out = (float*)d_out;

    const int n = in_sizes[0] / 3;   // 100000
    const int e = in_sizes[2] / 2;   // 3200000
    const int* src = ei;
    const int* dst = ei + e;

    // workspace layout (pairs dies before feature buffers are born -> alias)
    char* ws = (char*)d_ws;
    size_t off = 0;
    float* dinv   = (float*)(ws + off); off += (size_t)n * 4;
    int*   cnt    = (int*)(ws + off);   off += (size_t)n * 4;
    int*   rowptr = (int*)(ws + off);   off += (size_t)n * 4;
    int*   bsum   = (int*)(ws + off);   off += 1024 * 4;
    int*   blkcnt = (int*)(ws + off);   off += (size_t)NBLK_BIN * NBKT * 4;
    int*   srcs   = (int*)(ws + off);   off += (size_t)e * 4;
    char*  alias  = ws + off;           // max(pairs 51.4MB, A_h+B_h+B_f 27.2MB)
    int2*  pairs  = (int2*)alias;
    uint*  A_h    = (uint*)alias;                    // n x 32 uints (64 halfs)
    uint*  B_h    = A_h + (size_t)n * 32;            // n x 32 uints
    float* B_f    = (float*)(B_h + (size_t)n * 32);  // n x 4 floats

    int nb = (n + 255) / 256;   // 391

    // ---- CSR build (round-3 structure) ----
    zero_cnt_kernel<<<nb, 256, 0, stream>>>(cnt, n);
    bin_kernel<<<NBLK_BIN, 256, 0, stream>>>(src, dst, cnt, pairs, blkcnt, e);
    dinv_kernel<<<nb, 256, 0, stream>>>(cnt, dinv, n);
    scan_partial_kernel<<<nb, 256, 0, stream>>>(cnt, rowptr, bsum, n);
    scan_sums_kernel<<<1, 512, 0, stream>>>(bsum, nb);
    add_offsets_kernel<<<nb, 256, 0, stream>>>(rowptr, bsum, n);
    fill_csr_kernel2<<<NBKT, 256, 0, stream>>>(pairs, blkcnt, rowptr, srcs, n);

    // ---- x0 (pre-scaled by dinv), half stride 8, in A_h (overwrites pairs) ----
    build_x0_h_kernel<<<nb, 256, 0, stream>>>(coords, at, emb, dinv, A_h, n);

    auto blocks = [](long long threads) { return (int)((threads + 255) / 256); };

    // L1: 6->32. agg width6(FPH2=4); gemm + bias + relu + dinv-prescale
    agg_h_kernel<4, false, false><<<blocks((long long)n * 4), 256, 0, stream>>>(
        A_h, dinv, rowptr, cnt, srcs, nullptr, B_h, n);
    gemm_h_kernel<6, 32, 16, true, true, true, false><<<blocks((long long)n * 16), 256, 0, stream>>>(
        B_h, W1, b1, dinv, A_h, 4, 16, n);

    // L2: 32->64. agg width32(FPH2=16); gemm + bias + relu + dinv-prescale
    agg_h_kernel<16, false, false><<<blocks((long long)n * 16), 256, 0, stream>>>(
        A_h, dinv, rowptr, cnt, srcs, nullptr, B_h, n);
    gemm_h_kernel<32, 64, 32, true, true, true, false><<<blocks((long long)n * 32), 256, 0, stream>>>(
        B_h, W2, b2, dinv, A_h, 16, 32, n);

    // L3: 64->64. agg width64(FPH2=32); gemm + bias + relu (no scale: L4 is post-agg)
    agg_h_kernel<32, false, false><<<blocks((long long)n * 32), 256, 0, stream>>>(
        A_h, dinv, rowptr, cnt, srcs, nullptr, B_h, n);
    gemm_h_kernel<64, 64, 32, true, true, false, false><<<blocks((long long)n * 32), 256, 0, stream>>>(
        B_h, W3, b3, dinv, A_h, 32, 32, n);

    // L4: 64->32 post-agg. gemm scale-only -> B_h; agg width32 + bias + relu -> A_h
    gemm_h_kernel<64, 32, 16, false, false, true, false><<<blocks((long long)n * 16), 256, 0, stream>>>(
        A_h, W4, nullptr, dinv, B_h, 32, 16, n);
    agg_h_kernel<16, true, true><<<blocks((long long)n * 16), 256, 0, stream>>>(
        B_h, dinv, rowptr, cnt, srcs, b4, A_h, n);

    // L5: 32->3 post-agg, fp32 path. gemm scale-only -> B_f; agg + bias -> out
    gemm_h_kernel<32, 3, 2, false, false, true, true><<<blocks((long long)n * 2), 256, 0, stream>>>(
        A_h, W5, nullptr, dinv, B_f, 16, 4, n);
    agg_f_kernel<3, 4, true, false><<<blocks((long long)n * 4), 256, 0, stream>>>(
        B_f, dinv, rowptr, cnt, srcs, b5, out, 4, 3, n);
}

// Round 6
// 455.596 us; speedup vs baseline: 1.7750x; 1.2576x over previous
//
#include <hip/hip_runtime.h>
#include <hip/hip_fp16.h>

#define NBLK_BIN 256   // bin blocks; chunking identical to r3/r5 -> same per-cell counts
#define NBKT 196       // ceil(100000/512) dst-buckets
#define BWIN 512       // nodes per bucket
#define CAP 128        // slots per (block,bucket); lambda=63.8, +8 sigma -> no overflow

typedef unsigned int uint;

union U32H2 { uint u; __half2 h; };

__device__ inline float2 h2_to_f2(uint u) {
    U32H2 c; c.u = u;
    return __half22float2(c.h);
}
__device__ inline uint f2_to_h2(float a, float b) {
    U32H2 c; c.h = __floats2half2_rn(a, b);
    return c.u;
}

// ---------------- CSR build: bin pass (no global atomics) ----------------
// 1024 thr/block for 16 waves/CU. Each block owns pairs[blk][bucket][0..CAP).
__global__ __launch_bounds__(1024) void bin_kernel(const int* __restrict__ src,
                                                   const int* __restrict__ dst,
                                                   int2* __restrict__ pairs,
                                                   int* __restrict__ blkcnt, int e) {
    __shared__ int lcnt[NBKT];
    int blk = blockIdx.x, tid = threadIdx.x;
    for (int t = tid; t < NBKT; t += 1024) lcnt[t] = 0;
    __syncthreads();
    int chunk = (e + NBLK_BIN - 1) / NBLK_BIN;
    int base = blk * chunk;
    int end = min(e, base + chunk);
    for (int i = base + tid; i < end; i += 1024) {
        int s = src[i], d = dst[i];
        int b = d >> 9;
        int pos = atomicAdd(&lcnt[b], 1);
        if (pos < CAP) pairs[((size_t)blk * NBKT + b) * CAP + pos] = make_int2(s, d);
    }
    __syncthreads();
    for (int t = tid; t < NBKT; t += 1024) blkcnt[blk * NBKT + t] = min(lcnt[t], CAP);
}

// ---------------- bucket totals -> exclusive bases (1 block) ----------------
__global__ __launch_bounds__(256) void bucket_scan_kernel(const int* __restrict__ blkcnt,
                                                          int* __restrict__ bucket_base) {
    __shared__ int bt[256];
    int tid = threadIdx.x;
    int sum = 0;
    if (tid < NBKT)
        for (int blk = 0; blk < NBLK_BIN; ++blk) sum += blkcnt[blk * NBKT + tid];
    bt[tid] = sum;
    __syncthreads();
    int v = bt[tid];
    for (int off = 1; off < 256; off <<= 1) {
        int t = (tid >= off) ? bt[tid - off] : 0;
        __syncthreads();
        bt[tid] += t;
        __syncthreads();
    }
    if (tid < NBKT) bucket_base[tid] = bt[tid] - v;
}

// ---------------- CSR build: fused fill (counts + scan + cnt/rowptr/dinv + srcs) ----------------
__global__ __launch_bounds__(512) void fill_kernel(const int2* __restrict__ pairs,
                                                   const int* __restrict__ blkcnt,
                                                   const int* __restrict__ bucket_base,
                                                   int* __restrict__ srcs,
                                                   int* __restrict__ cnt,
                                                   int* __restrict__ rowptr,
                                                   float* __restrict__ dinv, int n) {
    __shared__ int lc[BWIN];     // counts, then cursors
    __shared__ int ps[BWIN];     // scan buffer
    __shared__ int sm[NBLK_BIN];
    int b = blockIdx.x, tid = threadIdx.x;   // 512 threads
    int nbase = b << 9;
    lc[tid] = 0;
    for (int t = tid; t < NBLK_BIN; t += 512) sm[t] = blkcnt[t * NBKT + b];
    __syncthreads();
    int wave = tid >> 6, lane = tid & 63;
    // pass 1: per-node counts
    for (int blk = wave; blk < NBLK_BIN; blk += 8) {
        int m = sm[blk];
        const int2* p = pairs + ((size_t)blk * NBKT + b) * CAP;
        for (int i = lane; i < m; i += 64) atomicAdd(&lc[p[i].y - nbase], 1);
    }
    __syncthreads();
    // exclusive scan of 512 counts (Hillis-Steele)
    int myc = lc[tid];
    ps[tid] = myc;
    __syncthreads();
    for (int off = 1; off < 512; off <<= 1) {
        int t = (tid >= off) ? ps[tid - off] : 0;
        __syncthreads();
        ps[tid] += t;
        __syncthreads();
    }
    int ex = ps[tid] - myc;
    int gbase = bucket_base[b];
    int vtx = nbase + tid;
    if (vtx < n) {
        cnt[vtx] = myc;
        rowptr[vtx] = gbase + ex;
        dinv[vtx] = rsqrtf(1.0f + (float)myc);   // +1: self-loop
    }
    __syncthreads();
    lc[tid] = ex;                // reuse as cursor
    __syncthreads();
    // pass 2: place srcs (writes land in this bucket's contiguous CSR span)
    for (int blk = wave; blk < NBLK_BIN; blk += 8) {
        int m = sm[blk];
        const int2* p = pairs + ((size_t)blk * NBKT + b) * CAP;
        for (int i = lane; i < m; i += 64) {
            int2 e2 = p[i];
            int o = atomicAdd(&lc[e2.y - nbase], 1);
            srcs[gbase + o] = e2.x;
        }
    }
}

// ---------------- input feature build: half, stride 8, pre-scaled by dinv ----------------

__global__ __launch_bounds__(256) void build_x0_h_kernel(const float* __restrict__ coords,
                                                         const int* __restrict__ at,
                                                         const float* __restrict__ emb,
                                                         const float* __restrict__ dinv,
                                                         uint* __restrict__ x, int n) {
    int v = blockIdx.x * 256 + threadIdx.x;
    if (v >= n) return;
    float dv = dinv[v];
    float c0 = coords[3 * v + 0] * dv;
    float c1 = coords[3 * v + 1] * dv;
    float c2 = coords[3 * v + 2] * dv;
    int t = at[v];
    float e0 = emb[3 * t + 0] * dv;
    float e1 = emb[3 * t + 1] * dv;
    float e2 = emb[3 * t + 2] * dv;
    uint* row = x + (size_t)v * 4;   // 8 halfs = 4 uints
    row[0] = f2_to_h2(c0, c1);
    row[1] = f2_to_h2(c2, e0);
    row[2] = f2_to_h2(e1, e2);
    row[3] = 0;                       // zero pad (features 6,7)
}

// ---------------- packed-half aggregation ----------------
// out[v] = op( dinv[v] * (in[v] + sum_{s in row(v)} in[s]) [+ b] ), rows
// pre-scaled by dinv[src]. Each lane owns 2 features. stride = FPH2 uints.
template <int FPH2, bool HAS_BIAS, bool RELU>
__global__ __launch_bounds__(256) void agg_h_kernel(const uint* __restrict__ in,
                                                    const float* __restrict__ dinv,
                                                    const int* __restrict__ rowptr,
                                                    const int* __restrict__ cnt,
                                                    const int* __restrict__ srcs,
                                                    const float* __restrict__ bias,
                                                    uint* __restrict__ out, int n) {
    int gid = blockIdx.x * 256 + threadIdx.x;
    int v = gid / FPH2, j2 = gid % FPH2;
    if (v >= n) return;
    float2 s0 = h2_to_f2(in[(size_t)v * FPH2 + j2]);   // self term
    float accx = s0.x, accy = s0.y;
    int start = rowptr[v];
    int len = cnt[v];
    int k = 0;
    for (; k + 4 <= len; k += 4) {
        int sA = srcs[start + k];
        int sB = srcs[start + k + 1];
        int sC = srcs[start + k + 2];
        int sD = srcs[start + k + 3];
        float2 fA = h2_to_f2(in[(size_t)sA * FPH2 + j2]);
        float2 fB = h2_to_f2(in[(size_t)sB * FPH2 + j2]);
        float2 fC = h2_to_f2(in[(size_t)sC * FPH2 + j2]);
        float2 fD = h2_to_f2(in[(size_t)sD * FPH2 + j2]);
        accx += (fA.x + fB.x) + (fC.x + fD.x);
        accy += (fA.y + fB.y) + (fC.y + fD.y);
    }
    for (; k < len; ++k) {
        int s = srcs[start + k];
        float2 f = h2_to_f2(in[(size_t)s * FPH2 + j2]);
        accx += f.x; accy += f.y;
    }
    float dv = dinv[v];
    accx *= dv; accy *= dv;
    if (HAS_BIAS) { accx += bias[2 * j2]; accy += bias[2 * j2 + 1]; }
    if (RELU) { accx = fmaxf(accx, 0.0f); accy = fmaxf(accy, 0.0f); }
    out[(size_t)v * FPH2 + j2] = f2_to_h2(accx, accy);
}

// ---------------- half GEMM: fp32 accumulate, packed-half (or fp32) out ----------------
template <int DIN, int DOUT, int DOUTH2, bool HAS_BIAS, bool RELU, bool SCALE, bool OUTF>
__global__ __launch_bounds__(256) void gemm_h_kernel(const uint* __restrict__ xin,
                                                     const float* __restrict__ W,
                                                     const float* __restrict__ bias,
                                                     const float* __restrict__ dinv,
                                                     void* __restrict__ xout,
                                                     int istride_u, int ostride, int n) {
    __shared__ float wlds[DIN * DOUT];
    for (int i = threadIdx.x; i < DIN * DOUT; i += 256) wlds[i] = W[i];
    __syncthreads();
    int gid = blockIdx.x * 256 + threadIdx.x;
    int v = gid / DOUTH2, j2 = gid % DOUTH2;
    if (v >= n) return;
    int j1 = 2 * j2;
    const uint* xr = xin + (size_t)v * istride_u;
    float acc0 = 0.0f, acc1 = 0.0f;
#pragma unroll
    for (int ku = 0; ku < DIN / 2; ++ku) {
        float2 xf = h2_to_f2(xr[ku]);
        int k = 2 * ku;
        acc0 = fmaf(xf.x, wlds[k * DOUT + j1], acc0);
        acc0 = fmaf(xf.y, wlds[(k + 1) * DOUT + j1], acc0);
        if (j1 + 1 < DOUT) {
            acc1 = fmaf(xf.x, wlds[k * DOUT + j1 + 1], acc1);
            acc1 = fmaf(xf.y, wlds[(k + 1) * DOUT + j1 + 1], acc1);
        }
    }
    if (HAS_BIAS) {
        acc0 += bias[j1];
        if (j1 + 1 < DOUT) acc1 += bias[j1 + 1];
    }
    if (RELU) { acc0 = fmaxf(acc0, 0.0f); acc1 = fmaxf(acc1, 0.0f); }
    if (SCALE) { float dv = dinv[v]; acc0 *= dv; acc1 *= dv; }
    if (OUTF) {
        float* o = (float*)xout + (size_t)v * ostride;
        o[j1] = acc0;
        if (j1 + 1 < DOUT) o[j1 + 1] = acc1;
    } else {
        ((uint*)xout)[(size_t)v * ostride + j2] = f2_to_h2(acc0, acc1);
    }
}

// ---------------- fp32 final aggregation (L5) ----------------
template <int F, int FP, bool HAS_BIAS, bool RELU>
__global__ __launch_bounds__(256) void agg_f_kernel(const float* __restrict__ in,
                                                    const float* __restrict__ dinv,
                                                    const int* __restrict__ rowptr,
                                                    const int* __restrict__ cnt,
                                                    const int* __restrict__ srcs,
                                                    const float* __restrict__ b,
                                                    float* __restrict__ out,
                                                    int istride, int ostride, int n) {
    int gid = blockIdx.x * 256 + threadIdx.x;
    int v = gid / FP, j = gid % FP;
    if (v >= n || j >= F) return;
    float dv = dinv[v];
    int start = rowptr[v];
    int len = cnt[v];
    float acc = in[(size_t)v * istride + j];
    int k = 0;
    for (; k + 4 <= len; k += 4) {
        int s0 = srcs[start + k];
        int s1 = srcs[start + k + 1];
        int s2 = srcs[start + k + 2];
        int s3 = srcs[start + k + 3];
        float a0 = in[(size_t)s0 * istride + j];
        float a1 = in[(size_t)s1 * istride + j];
        float a2 = in[(size_t)s2 * istride + j];
        float a3 = in[(size_t)s3 * istride + j];
        acc += (a0 + a1) + (a2 + a3);
    }
    for (; k < len; ++k) acc += in[(size_t)srcs[start + k] * istride + j];
    float val = acc * dv;
    if (HAS_BIAS) val += b[j];
    if (RELU) val = fmaxf(val, 0.0f);
    out[(size_t)v * ostride + j] = val;
}

// ---------------- driver ----------------

extern "C" void kernel_launch(void* const* d_in, const int* in_sizes, int n_in,
                              void* d_out, int out_size, void* d_ws, size_t ws_size,
                              hipStream_t stream) {
    const float* coords = (const float*)d_in[0];
    const int* at       = (const int*)d_in[1];
    const int* ei       = (const int*)d_in[2];
    const float* emb    = (const float*)d_in[3];
    const float* W1 = (const float*)d_in[4];  const float* b1 = (const float*)d_in[5];
    const float* W2 = (const float*)d_in[6];  const float* b2 = (const float*)d_in[7];
    const float* W3 = (const float*)d_in[8];  const float* b3 = (const float*)d_in[9];
    const float* W4 = (const float*)d_in[10]; const float* b4 = (const float*)d_in[11];
    const float* W5 = (const float*)d_in[12]; const float* b5 = (const float*)d_in[13];
    float* out = (float*)d_out;

    const int n = in_sizes[0] / 3;   // 100000
    const int e = in_sizes[2] / 2;   // 3200000
    const int* src = ei;
    const int* dst = ei + e;

    // workspace layout (pairs dies before feature buffers are born -> alias)
    char* ws = (char*)d_ws;
    size_t off = 0;
    float* dinv   = (float*)(ws + off); off += (size_t)n * 4;
    int*   cnt    = (int*)(ws + off);   off += (size_t)n * 4;
    int*   rowptr = (int*)(ws + off);   off += (size_t)n * 4;
    int*   bbase  = (int*)(ws + off);   off += 1024;
    int*   blkcnt = (int*)(ws + off);   off += (size_t)NBLK_BIN * NBKT * 4;
    int*   srcs   = (int*)(ws + off);   off += (size_t)e * 4;
    char*  alias  = ws + off;           // max(pairs 51.4MB, A_h+B_h+B_f 27.2MB)
    int2*  pairs  = (int2*)alias;
    uint*  A_h    = (uint*)alias;                    // n x 32 uints (64 halfs)
    uint*  B_h    = A_h + (size_t)n * 32;            // n x 32 uints
    float* B_f    = (float*)(B_h + (size_t)n * 32);  // n x 4 floats

    int nb = (n + 255) / 256;   // 391

    // ---- CSR build ----
    bin_kernel<<<NBLK_BIN, 1024, 0, stream>>>(src, dst, pairs, blkcnt, e);
    bucket_scan_kernel<<<1, 256, 0, stream>>>(blkcnt, bbase);
    fill_kernel<<<NBKT, 512, 0, stream>>>(pairs, blkcnt, bbase, srcs, cnt, rowptr, dinv, n);

    // ---- x0 (pre-scaled by dinv), half stride 8, in A_h (overwrites pairs) ----
    build_x0_h_kernel<<<nb, 256, 0, stream>>>(coords, at, emb, dinv, A_h, n);

    auto blocks = [](long long threads) { return (int)((threads + 255) / 256); };

    // L1: 6->32. agg width6(FPH2=4); gemm + bias + relu + dinv-prescale
    agg_h_kernel<4, false, false><<<blocks((long long)n * 4), 256, 0, stream>>>(
        A_h, dinv, rowptr, cnt, srcs, nullptr, B_h, n);
    gemm_h_kernel<6, 32, 16, true, true, true, false><<<blocks((long long)n * 16), 256, 0, stream>>>(
        B_h, W1, b1, dinv, A_h, 4, 16, n);

    // L2: 32->64. agg width32(FPH2=16); gemm + bias + relu + dinv-prescale
    agg_h_kernel<16, false, false><<<blocks((long long)n * 16), 256, 0, stream>>>(
        A_h, dinv, rowptr, cnt, srcs, nullptr, B_h, n);
    gemm_h_kernel<32, 64, 32, true, true, true, false><<<blocks((long long)n * 32), 256, 0, stream>>>(
        B_h, W2, b2, dinv, A_h, 16, 32, n);

    // L3: 64->64. agg width64(FPH2=32); gemm + bias + relu (no scale: L4 is post-agg)
    agg_h_kernel<32, false, false><<<blocks((long long)n * 32), 256, 0, stream>>>(
        A_h, dinv, rowptr, cnt, srcs, nullptr, B_h, n);
    gemm_h_kernel<64, 64, 32, true, true, false, false><<<blocks((long long)n * 32), 256, 0, stream>>>(
        B_h, W3, b3, dinv, A_h, 32, 32, n);

    // L4: 64->32 post-agg. gemm scale-only -> B_h; agg width32 + bias + relu -> A_h
    gemm_h_kernel<64, 32, 16, false, false, true, false><<<blocks((long long)n * 16), 256, 0, stream>>>(
        A_h, W4, nullptr, dinv, B_h, 32, 16, n);
    agg_h_kernel<16, true, true><<<blocks((long long)n * 16), 256, 0, stream>>>(
        B_h, dinv, rowptr, cnt, srcs, b4, A_h, n);

    // L5: 32->3 post-agg, fp32 path. gemm scale-only -> B_f; agg + bias -> out
    gemm_h_kernel<32, 3, 2, false, false, true, true><<<blocks((long long)n * 2), 256, 0, stream>>>(
        A_h, W5, nullptr, dinv, B_f, 16, 4, n);
    agg_f_kernel<3, 4, true, false><<<blocks((long long)n * 4), 256, 0, stream>>>(
        B_f, dinv, rowptr, cnt, srcs, b5, out, 4, 3, n);
}